// Round 7
// baseline (570.912 us; speedup 1.0000x reference)
//
#include <hip/hip_runtime.h>
#include <math.h>

typedef __attribute__((ext_vector_type(2))) _Float16 half2_t;
typedef __attribute__((ext_vector_type(2))) float floatx2;
typedef unsigned long long u64;

static constexpr int S    = 771;   // NB_LABELS*MAX_DEPTH + EXTRA
static constexpr int Tn   = 128;
static constexpr int Bn   = 32;
static constexpr int BOSs = 0;
static constexpr int EOSs = 1;

static constexpr int JPAD  = 832;            // 13 * 64 state pad (output AND inner)
static constexpr int JB    = 13;             // blocks per batch
static constexpr int ROWS  = 64;             // output rows per block (= lanes)
static constexpr int NCH   = 4;              // K-chunks (= waves per block)
static constexpr int SL    = JPAD / NCH;     // 208 fp8 per thread K-slice
static constexpr int CH    = SL / 16;        // 13 x b128 per thread
static constexpr int EBLK  = NCH * CH * ROWS * 16;   // 53248 B per jblk
static constexpr int ETOT  = JB * EBLK;              // 692224 B
static constexpr int NG    = JB * 33;        // 429 u64 exchanged per (batch,step)
static constexpr int XSTR  = 432;            // padded stride (u64) per (parity,batch)
static constexpr float CBIAS = 6.0f;         // f16-overflow headroom in normalizer

__device__ __forceinline__ float wave_max_bfly(float v) {   // result in ALL lanes
    #pragma unroll
    for (int off = 32; off > 0; off >>= 1) v = fmaxf(v, __shfl_xor(v, off));
    return v;
}
__device__ __forceinline__ float wave_sum_f(float v) {
    #pragma unroll
    for (int off = 32; off > 0; off >>= 1) v += __shfl_down(v, off);
    return v;
}

union U32H { unsigned u; half2_t h; };
union HU16 { _Float16 h; unsigned short u; };

__device__ __forceinline__ u64 ald64(const u64* p) {
    return __hip_atomic_load((u64*)p, __ATOMIC_RELAXED, __HIP_MEMORY_SCOPE_AGENT);
}
__device__ __forceinline__ void ast64(u64* p, u64 v) {
    __hip_atomic_store(p, v, __ATOMIC_RELAXED, __HIP_MEMORY_SCOPE_AGENT);
}
__device__ __forceinline__ u64 pack(unsigned tag, unsigned payload) {
    return ((u64)tag << 32) | (u64)payload;
}

// fp8 e4m3fn (OCP) encode for x in {0} U [~0.9, ~1.11] (positive normals only)
__device__ __forceinline__ unsigned char enc_e4m3(float x) {
    if (x <= 0.f) return 0;
    unsigned b = __float_as_uint(x);
    int e = (int)((b >> 23) & 0xff) - 127;
    unsigned m3 = ((b & 0x7fffff) + (1u << 19)) >> 20;   // RN
    if (m3 == 8) { m3 = 0; e += 1; }
    int ee = e + 7;
    if (ee < 1) return 0;
    if (ee > 15) { ee = 15; m3 = 7; }
    return (unsigned char)((ee << 3) | m3);
}

// decode 2 packed fp8 (byte pair HI?2,3:0,1 of v) -> 2 f32.
// HI must be a compile-time constant: the builtin requires an immediate.
#if __has_builtin(__builtin_amdgcn_cvt_pk_f32_fp8)
template <bool HI>
__device__ __forceinline__ floatx2 dec2(unsigned v) {
    return __builtin_amdgcn_cvt_pk_f32_fp8((int)v, HI);
}
#else
template <bool HI>
__device__ __forceinline__ floatx2 dec2(unsigned v) {
    unsigned b0 = (v >> (HI ? 16 : 0)) & 0xff, b1 = (v >> (HI ? 24 : 8)) & 0xff;
    floatx2 r;   // e4m3fn positive normal -> f32: bits = (b<<20) + 0x3C000000
    r.x = b0 ? __uint_as_float((b0 << 20) + 0x3C000000u) : 0.f;
    r.y = b1 ? __uint_as_float((b1 << 20) + 0x3C000000u) : 0.f;
    return r;
}
#endif

// ---------------------------------------------------------------------------
// Prep: fp8-e4m3 exp-transition table (swizzled) + exp(trans[:,EOS]) column.
// eswz[(((jblk*4+w)*13+kk)*64+lane)*16+e] = e4m3(exp(trans[i][j])),
//   i = w*208 + kk*16 + e, j = jblk*64 + lane.
// -> fwd kernel's LDS staging load is lane-contiguous 16B, and the in-LDS
// layout gives conflict-free full-wave ds_read_b128 in the dot loop.
// exp(-1e9) -> 0 exactly: forbidden transitions vanish from the dots.
// ---------------------------------------------------------------------------
extern "C" __global__ void build_tabs(const float* __restrict__ trans,
                                      unsigned char* __restrict__ eswz,
                                      float* __restrict__ eteos) {
    int idx = blockIdx.x * blockDim.x + threadIdx.x;
    if (idx < JPAD)
        eteos[idx] = (idx < S) ? __expf(trans[idx * S + EOSs]) : 0.f;
    if (idx >= ETOT) return;
    int e = idx & 15;
    int q = idx >> 4;
    int lane = q & 63;  q >>= 6;
    int kk = q % 13;
    int h  = q / 13;
    int w  = h & 3, jblk = h >> 2;
    int i = w * SL + kk * 16 + e;
    int j = jblk * ROWS + lane;
    float v = 0.f;
    if (i < S && j < S) v = __expf(trans[i * S + j]);
    eswz[idx] = enc_e4m3(v);
}

// ---------------------------------------------------------------------------
// Gold-path scores (unchanged, passing since round 1).
// ---------------------------------------------------------------------------
extern "C" __global__ __launch_bounds__(Tn)
void crf_scores(const float* __restrict__ em, const int* __restrict__ tags,
                const float* __restrict__ mask, const float* __restrict__ trans,
                float* __restrict__ scores) {
    const int b = blockIdx.x, t = threadIdx.x;
    const int lane = t & 63, wid = t >> 6;
    __shared__ float redv[2], redm[2];

    float mk = mask[b * Tn + t];
    float val = 0.f;
    if (t > 0) {
        int cur  = tags[b * Tn + t];
        int prev = tags[b * Tn + t - 1];
        val = (em[((size_t)b * Tn + t) * S + cur] + trans[prev * S + cur]) * mk;
    }
    float v  = wave_sum_f(val);
    float ms = wave_sum_f(mk);
    if (lane == 0) { redv[wid] = v; redm[wid] = ms; }
    __syncthreads();
    if (t == 0) {
        float tot  = redv[0] + redv[1];
        float msum = redm[0] + redm[1];
        int last  = (int)(msum + 0.5f) - 1;
        int first = tags[b * Tn];
        int lastt = tags[b * Tn + last];
        scores[b] = tot + trans[BOSs * S + first]
                        + em[((size_t)b * Tn) * S + first]
                        + trans[lastt * S + EOSs];
    }
}

// publish (wave 0 only): own 64 rows' alpha -> p=exp(alpha-C) f16 pairs + chunk
// max, as 33 tagged u64 agent atomics. Exchange stream carries its own sync.
__device__ __forceinline__ void publish(u64* W, int jblk, unsigned tag,
                                        float af, float C, int lane) {
    float xf = __expf(af - C);          // -inf -> 0 exactly
    HU16 cv; cv.h = (_Float16)xf;
    unsigned us = cv.u;
    unsigned aa = (unsigned)__shfl((int)us, 2 * lane);
    unsigned bb = (unsigned)__shfl((int)us, 2 * lane + 1);
    float mc = wave_max_bfly(af);
    u64* base = W + 33 * jblk;
    if (lane < 32)  ast64(base + lane, pack(tag, aa | (bb << 16)));
    if (lane == 32) ast64(base + 32,   pack(tag, __float_as_uint(mc)));
}

// ---------------------------------------------------------------------------
// Forward algorithm. Change vs r5: E lives in LDS as fp8 (deterministically
// resident -- r3..r5 VGPR counts proved the compiler re-streamed the
// "register" E fragment from L2 every step). Dot = ds_read_b128(16 fp8) +
// p-broadcast b128 + v_cvt_pk_f32_fp8 + FMA. Exchange protocol unchanged:
// tagged u64 {t, 2xf16 p} agent atomics, producer-normalized by C_t.
// ---------------------------------------------------------------------------
extern "C" __global__ __launch_bounds__(256, 2)
void crf_fwd(const float* __restrict__ em, const float* __restrict__ mask,
             const float* __restrict__ trans, const unsigned char* __restrict__ eswz,
             const float* __restrict__ eteos, const float* __restrict__ scores,
             u64* __restrict__ xb, float* __restrict__ out) {
    const int jblk = blockIdx.x, b = blockIdx.y;
    const int tid = threadIdx.x, lane = tid & 63, w = tid >> 6;
    const int j0 = jblk * ROWS;

    __shared__ __align__(16) unsigned char Elds[EBLK];  // 52 KB fp8 E tile
    __shared__ __align__(16) float p2f[JPAD];           // exchanged p as f32
    __shared__ float part[256];
    __shared__ float mch[16];
    __shared__ float reds[NCH];
    __shared__ float cshare;

    // ---- one-time: stage this block's E tile into LDS (13 x 1KB/wave) ----
    {
        const unsigned char* gsrc = eswz + (size_t)(jblk * NCH + w) * (CH * 1024);
        unsigned char* ldst = Elds + w * (CH * 1024);
        #pragma unroll
        for (int kk = 0; kk < CH; ++kk) {
            const float4 v = *(const float4*)(gsrc + kk * 1024 + lane * 16);
            *(float4*)(ldst + kk * 1024 + lane * 16) = v;
        }
    }

    // wave-0 per-lane state: alpha of own row + running normalizer
    float af = -INFINITY;
    float Cuse = CBIAS;

    if (w == 0) {
        int j = j0 + lane;
        if (j < S) af = trans[BOSs * S + j] + em[((size_t)b * Tn + 0) * S + j];
        publish(xb + ((size_t)0 * Bn + b) * XSTR, jblk, 0u, af, CBIAS, lane);
    }

    const int g0 = tid * 2, g1 = g0 + 1;
    const bool act0 = (g0 < NG), act1 = (g1 < NG);

    // ---- 127 sequential steps ----
    for (int t = 1; t < Tn; ++t) {
        const u64* R = xb + ((size_t)((t - 1) & 1) * Bn + b) * XSTR;
        u64*       W = xb + ((size_t)((t    ) & 1) * Bn + b) * XSTR;

        // epilogue operands independent of alpha: issue before the poll
        float emv = 0.f, mval = 0.f;
        if (w == 0) {
            const int j = j0 + lane;
            if (j < S) emv = em[((size_t)b * Tn + t) * S + j];
            mval = mask[b * Tn + t];
        }

        // ---- poll tagged stream: sync == data arrival ----
        const unsigned tg = (unsigned)(t - 1);
        u64 q0 = 0, q1 = 0;
        bool ok = !act0;
        while (true) {
            if (!ok) {
                q0 = ald64(R + g0);
                bool o0 = ((unsigned)(q0 >> 32) == tg);
                bool o1 = true;
                if (act1) { q1 = ald64(R + g1); o1 = ((unsigned)(q1 >> 32) == tg); }
                ok = o0 & o1;
            }
            if (__syncthreads_and(ok)) break;
        }

        // ---- unpack: f16 pairs -> f32 LDS; chunk maxes -> mch ----
        if (act0) {
            int c = g0 / 33, sl = g0 - c * 33;
            if (sl == 32) mch[c] = __uint_as_float((unsigned)q0);
            else {
                U32H v; v.u = (unsigned)q0;
                p2f[c * 64 + sl * 2]     = (float)v.h.x;
                p2f[c * 64 + sl * 2 + 1] = (float)v.h.y;
            }
        }
        if (act1) {
            int c = g1 / 33, sl = g1 - c * 33;
            if (sl == 32) mch[c] = __uint_as_float((unsigned)q1);
            else {
                U32H v; v.u = (unsigned)q1;
                p2f[c * 64 + sl * 2]     = (float)v.h.x;
                p2f[c * 64 + sl * 2 + 1] = (float)v.h.y;
            }
        }
        __syncthreads();

        // wave 0: next normalizer from this step's chunk maxes
        float Cnew = 0.f;
        if (w == 0) {
            float mv = (lane < 13) ? mch[lane] : -INFINITY;
            Cnew = wave_max_bfly(mv) + CBIAS;
        }

        // ---- dot: LDS fp8 E (conflict-free b128) x LDS f32 p (broadcast) ----
        float acc = 0.f;
        const unsigned char* Ew = Elds + w * (CH * 1024) + lane * 16;
        const float* pw = p2f + w * SL;
        #pragma unroll
        for (int kk = 0; kk < CH; ++kk) {
            const uint4  ev = *(const uint4*)(Ew + kk * 1024);
            const float4 pa = *(const float4*)(pw + kk * 16);
            const float4 pb = *(const float4*)(pw + kk * 16 + 4);
            const float4 pc = *(const float4*)(pw + kk * 16 + 8);
            const float4 pd = *(const float4*)(pw + kk * 16 + 12);
            floatx2 e0 = dec2<false>(ev.x), e1 = dec2<true>(ev.x);
            floatx2 e2 = dec2<false>(ev.y), e3 = dec2<true>(ev.y);
            floatx2 e4 = dec2<false>(ev.z), e5 = dec2<true>(ev.z);
            floatx2 e6 = dec2<false>(ev.w), e7 = dec2<true>(ev.w);
            acc += e0.x * pa.x + e0.y * pa.y + e1.x * pa.z + e1.y * pa.w;
            acc += e2.x * pb.x + e2.y * pb.y + e3.x * pb.z + e3.y * pb.w;
            acc += e4.x * pc.x + e4.y * pc.y + e5.x * pc.z + e5.y * pc.w;
            acc += e6.x * pd.x + e6.y * pd.y + e7.x * pd.z + e7.y * pd.w;
        }
        part[w * ROWS + lane] = acc;
        __syncthreads();

        // ---- epilogue (wave 0): alpha' = Cuse + log(dot) + em, publish ----
        if (w == 0) {
            float s4 = part[lane] + part[ROWS + lane]
                     + part[2 * ROWS + lane] + part[3 * ROWS + lane];
            float nv = Cuse + __logf(s4) + emv;   // log(0)=-inf for dead rows
            af = (mval > 0.f) ? nv : af;
            publish(W, jblk, (unsigned)t, af, Cnew, lane);
            if (lane == 0) cshare = Cnew;
            Cuse = Cnew;
        }
        // next poll's __syncthreads_and protects all LDS reuse
    }

    // ---- log_Z (block jblk==0 of each batch): dot with exp(trans[:,EOS]) ----
    if (jblk == 0) {
        const u64* R = xb + ((size_t)((Tn - 1) & 1) * Bn + b) * XSTR;
        const unsigned tg = (unsigned)(Tn - 1);
        u64 q0 = 0, q1 = 0;
        bool ok = !act0;
        while (true) {
            if (!ok) {
                q0 = ald64(R + g0);
                bool o0 = ((unsigned)(q0 >> 32) == tg);
                bool o1 = true;
                if (act1) { q1 = ald64(R + g1); o1 = ((unsigned)(q1 >> 32) == tg); }
                ok = o0 & o1;
            }
            if (__syncthreads_and(ok)) break;
        }
        float lsum = 0.f;
        if (act0) {
            int c = g0 / 33, sl = g0 - c * 33;
            if (sl < 32) {
                U32H v; v.u = (unsigned)q0;
                int st = c * 64 + sl * 2;
                lsum += (float)v.h.x * eteos[st] + (float)v.h.y * eteos[st + 1];
            }
        }
        if (act1) {
            int c = g1 / 33, sl = g1 - c * 33;
            if (sl < 32) {
                U32H v; v.u = (unsigned)q1;
                int st = c * 64 + sl * 2;
                lsum += (float)v.h.x * eteos[st] + (float)v.h.y * eteos[st + 1];
            }
        }
        lsum = wave_sum_f(lsum);
        if (lane == 0) reds[w] = lsum;
        __syncthreads();
        if (tid == 0) {
            float tot = reds[0] + reds[1] + reds[2] + reds[3];
            float logz = cshare + __logf(tot);   // x already exp(alpha - C_127)
            atomicAdd(out, -(scores[b] - logz));
        }
    }
}

extern "C" void kernel_launch(void* const* d_in, const int* in_sizes, int n_in,
                              void* d_out, int out_size, void* d_ws, size_t ws_size,
                              hipStream_t stream) {
    const float* em    = (const float*)d_in[0];
    const int*   tags  = (const int*)d_in[1];
    const float* mask  = (const float*)d_in[2];
    const float* trans = (const float*)d_in[3];
    float* out = (float*)d_out;

    char* ws = (char*)d_ws;
    size_t off = 0;
    unsigned char* eswz = (unsigned char*)(ws + off);
    off += (size_t)ETOT;
    off = (off + 255) & ~(size_t)255;
    float* eteos = (float*)(ws + off); off += JPAD * sizeof(float);
    off = (off + 255) & ~(size_t)255;
    u64* xb = (u64*)(ws + off);        off += (size_t)2 * Bn * XSTR * sizeof(u64);
    off = (off + 255) & ~(size_t)255;
    float* scores = (float*)(ws + off); off += Bn * sizeof(float);

    // ws re-poisoned 0xAA pre-launch: stale tags (0xAAAAAAAA) never match t<128
    (void)hipMemsetAsync(out, 0, sizeof(float), stream);

    build_tabs<<<(ETOT + 255) / 256, 256, 0, stream>>>(trans, eswz, eteos);
    crf_scores<<<Bn, Tn, 0, stream>>>(em, tags, mask, trans, scores);
    crf_fwd<<<dim3(JB, Bn), 256, 0, stream>>>(em, mask, trans, eswz, eteos,
                                              scores, xb, out);
}

// Round 8
// 403.391 us; speedup vs baseline: 1.4153x; 1.4153x over previous
//
#include <hip/hip_runtime.h>
#include <math.h>

typedef unsigned long long u64;

static constexpr int S    = 771;   // NB_LABELS*MAX_DEPTH + EXTRA
static constexpr int Tn   = 128;
static constexpr int Bn   = 32;
static constexpr int BOSs = 0;
static constexpr int EOSs = 1;

static constexpr int JPAD  = 832;          // 13 * 64 state pad
static constexpr int JB    = 13;           // blocks per batch
static constexpr int ROWS  = 64;           // output rows per block (= lanes)
static constexpr int NCH   = 4;            // inner split across 4 waves
static constexpr int SL    = JPAD / NCH;   // 208 i8 inner slice per thread
static constexpr int CH    = SL / 16;      // 13 x b128 per thread
static constexpr int EBLK  = NCH * CH * ROWS * 16;   // 53248 B per jblk
static constexpr int ETOT  = JB * EBLK;              // 692224 B
static constexpr int NG    = JB * 17;      // 221 u64 exchanged per (batch,step)
static constexpr int XSTR  = 224;          // padded stride (u64) per (parity,batch)
static constexpr float CB  = 8.0f;         // normalizer headroom (drift bound)
static constexpr float C0V = 4.5f;         // fixed normalizer for t=0 publish

__device__ __forceinline__ float wave_max_bfly(float v) {   // result in ALL lanes
    #pragma unroll
    for (int off = 32; off > 0; off >>= 1) v = fmaxf(v, __shfl_xor(v, off));
    return v;
}
__device__ __forceinline__ float wave_sum_f(float v) {
    #pragma unroll
    for (int off = 32; off > 0; off >>= 1) v += __shfl_down(v, off);
    return v;
}

__device__ __forceinline__ u64 ald64(const u64* p) {
    return __hip_atomic_load((u64*)p, __ATOMIC_RELAXED, __HIP_MEMORY_SCOPE_AGENT);
}
__device__ __forceinline__ void ast64(u64* p, u64 v) {
    __hip_atomic_store(p, v, __ATOMIC_RELAXED, __HIP_MEMORY_SCOPE_AGENT);
}
__device__ __forceinline__ u64 pack(unsigned tag, unsigned payload) {
    return ((u64)tag << 32) | (u64)payload;
}

// i8 x i8 + i32 dot (both operands in [0,127] here, so signed == unsigned)
#if __has_builtin(__builtin_amdgcn_sdot4)
__device__ __forceinline__ int dot4i(unsigned a, unsigned b, int c) {
    return __builtin_amdgcn_sdot4((int)a, (int)b, c, false);
}
#else
__device__ __forceinline__ int dot4i(unsigned a, unsigned b, int c) {
    c += (int)(a & 0xff)         * (int)(b & 0xff);
    c += (int)((a >> 8) & 0xff)  * (int)((b >> 8) & 0xff);
    c += (int)((a >> 16) & 0xff) * (int)((b >> 16) & 0xff);
    c += (int)((a >> 24) & 0xff) * (int)((b >> 24) & 0xff);
    return c;
}
#endif

// ---------------------------------------------------------------------------
// Prep: i8 exp-transition table (swizzled) + exp(trans[:,EOS]) f32 column.
// eswz[jblk][w][kk][lane][16] = round(115*exp(trans[i][j])), value in [0,127],
//   i = w*208 + kk*16 + e (inner/source), j = jblk*64 + lane (output row).
// exp(-1e9)*115 -> 0: forbidden transitions vanish from the integer dots.
// ---------------------------------------------------------------------------
extern "C" __global__ void build_tabs(const float* __restrict__ trans,
                                      unsigned char* __restrict__ eswz,
                                      float* __restrict__ eteos) {
    int idx = blockIdx.x * blockDim.x + threadIdx.x;
    if (idx < JPAD)
        eteos[idx] = (idx < S) ? __expf(trans[idx * S + EOSs]) : 0.f;
    if (idx >= ETOT) return;
    int e = idx & 15;
    int q = idx >> 4;
    int lane = q & 63;  q >>= 6;
    int kk = q % 13;
    int h  = q / 13;
    int w  = h & 3, jblk = h >> 2;
    int i = w * SL + kk * 16 + e;
    int j = jblk * ROWS + lane;
    float v = 0.f;
    if (i < S && j < S) v = 115.f * __expf(trans[i * S + j]);
    int q8 = (int)(v + 0.5f);
    if (q8 > 127) q8 = 127;
    eswz[idx] = (unsigned char)q8;
}

// ---------------------------------------------------------------------------
// Gold-path scores (unchanged, passing since round 1). Exact fp32: carries the
// -1e9 forbidden-transition terms that dominate the output magnitude.
// ---------------------------------------------------------------------------
extern "C" __global__ __launch_bounds__(Tn)
void crf_scores(const float* __restrict__ em, const int* __restrict__ tags,
                const float* __restrict__ mask, const float* __restrict__ trans,
                float* __restrict__ scores) {
    const int b = blockIdx.x, t = threadIdx.x;
    const int lane = t & 63, wid = t >> 6;
    __shared__ float redv[2], redm[2];

    float mk = mask[b * Tn + t];
    float val = 0.f;
    if (t > 0) {
        int cur  = tags[b * Tn + t];
        int prev = tags[b * Tn + t - 1];
        val = (em[((size_t)b * Tn + t) * S + cur] + trans[prev * S + cur]) * mk;
    }
    float v  = wave_sum_f(val);
    float ms = wave_sum_f(mk);
    if (lane == 0) { redv[wid] = v; redm[wid] = ms; }
    __syncthreads();
    if (t == 0) {
        float tot  = redv[0] + redv[1];
        float msum = redm[0] + redm[1];
        int last  = (int)(msum + 0.5f) - 1;
        int first = tags[b * Tn];
        int lastt = tags[b * Tn + last];
        scores[b] = tot + trans[BOSs * S + first]
                        + em[((size_t)b * Tn) * S + first]
                        + trans[lastt * S + EOSs];
    }
}

// publish (wave 0 only): own 64 rows -> p8 = round(127*exp(alpha-C)) packed
// 4/byte-lane into 16 u64 + 1 u64 carrying the f32 chunk max. 17 tagged
// agent-atomic stores; the tag stream IS the sync.
__device__ __forceinline__ void publish(u64* W, int jblk, unsigned tag,
                                        float af, float C, int lane) {
    float xf = fminf(127.f, 127.f * __expf(af - C));   // -inf/-1e9 -> 0
    int xi = (int)(xf + 0.5f);
    int b0 = __shfl(xi, (4 * lane) & 63);
    int b1 = __shfl(xi, (4 * lane + 1) & 63);
    int b2 = __shfl(xi, (4 * lane + 2) & 63);
    int b3 = __shfl(xi, (4 * lane + 3) & 63);
    unsigned payload = (unsigned)b0 | ((unsigned)b1 << 8)
                     | ((unsigned)b2 << 16) | ((unsigned)b3 << 24);
    float mc = wave_max_bfly(af);
    u64* base = W + 17 * jblk;
    if (lane < 16)  ast64(base + lane, pack(tag, payload));
    if (lane == 16) ast64(base + 16,   pack(tag, __float_as_uint(mc)));
}

// ---------------------------------------------------------------------------
// Forward algorithm. r8 changes vs r7: (1) dot is i8 v_dot4 on LDS-resident
// i8 E -- ~80 inst/thread/step vs r7's ~380 (r7 proved serial-path compute
// costs 1:1); (2) exchange is u8 p, 221 u64/step -> exactly one poll load
// per thread. alpha' = C - log(115*127) + log(acc) + em, exact fp32 epilogue.
// C_t = Mb_{t-1} + 8, derived redundantly by every block from the exchanged
// f32 chunk maxes (no extra sync hop).
// ---------------------------------------------------------------------------
extern "C" __global__ __launch_bounds__(256, 2)
void crf_fwd(const float* __restrict__ em, const float* __restrict__ mask,
             const float* __restrict__ trans, const unsigned char* __restrict__ eswz,
             const float* __restrict__ eteos, const float* __restrict__ scores,
             u64* __restrict__ xb, float* __restrict__ out) {
    const int jblk = blockIdx.x, b = blockIdx.y;
    const int tid = threadIdx.x, lane = tid & 63, w = tid >> 6;
    const int j0 = jblk * ROWS;

    __shared__ __align__(16) unsigned char Elds[EBLK];  // 52 KB i8 E tile
    __shared__ __align__(16) unsigned pbuf[JPAD / 4];   // 208 u32 = 832 p8
    __shared__ int   part[256];
    __shared__ float mch[16];
    __shared__ float reds[NCH];
    __shared__ float cshare;

    const float KLOG  = __logf(115.f * 127.f);
    const float KL127 = __logf(127.f);

    // ---- one-time: stage this block's E tile into LDS (13 x 1KB/wave) ----
    {
        const unsigned char* gsrc = eswz + (size_t)(jblk * NCH + w) * (CH * 1024);
        unsigned char* ldst = Elds + w * (CH * 1024);
        #pragma unroll
        for (int kk = 0; kk < CH; ++kk) {
            const float4 v = *(const float4*)(gsrc + kk * 1024 + lane * 16);
            *(float4*)(ldst + kk * 1024 + lane * 16) = v;
        }
    }

    // wave-0 per-lane state: alpha of own row + normalizer of consumed x
    float af = -INFINITY;
    float Cuse = C0V;

    if (w == 0) {
        int j = j0 + lane;
        if (j < S) af = trans[BOSs * S + j] + em[((size_t)b * Tn + 0) * S + j];
        publish(xb + ((size_t)0 * Bn + b) * XSTR, jblk, 0u, af, C0V, lane);
    }

    const bool act = (tid < NG);
    const int c17 = tid / 17, s17 = tid - c17 * 17;

    // ---- 127 sequential steps ----
    for (int t = 1; t < Tn; ++t) {
        const u64* R = xb + ((size_t)((t - 1) & 1) * Bn + b) * XSTR;
        u64*       W = xb + ((size_t)((t    ) & 1) * Bn + b) * XSTR;

        // epilogue operands independent of alpha: issue before the poll
        float emv = 0.f, mval = 0.f;
        if (w == 0) {
            const int j = j0 + lane;
            if (j < S) emv = em[((size_t)b * Tn + t) * S + j];
            mval = mask[b * Tn + t];
        }

        // ---- poll tagged stream: ONE u64 per thread, sync == data arrival ----
        const unsigned tg = (unsigned)(t - 1);
        u64 q = 0;
        bool ok = !act;
        while (true) {
            if (!ok) { q = ald64(R + tid); ok = ((unsigned)(q >> 32) == tg); }
            if (__syncthreads_and(ok)) break;
        }

        // ---- unpack: packed p8 -> LDS; chunk maxes -> mch ----
        if (act) {
            if (s17 == 16) mch[c17] = __uint_as_float((unsigned)q);
            else           pbuf[c17 * 16 + s17] = (unsigned)q;
        }
        __syncthreads();

        // wave 0: next normalizer from this step's chunk maxes
        float Cnew = 0.f;
        if (w == 0) {
            float mv = (lane < JB) ? mch[lane] : -INFINITY;
            Cnew = wave_max_bfly(mv) + CB;
        }

        // ---- dot: LDS i8 E (b128) x LDS packed p8 (b128 broadcast) ----
        int acc = 0;
        const unsigned char* Ew = Elds + w * (CH * 1024) + lane * 16;
        const uint4* pb4 = (const uint4*)pbuf;
        #pragma unroll
        for (int kk = 0; kk < CH; ++kk) {
            const uint4 ev = *(const uint4*)(Ew + kk * 1024);
            const uint4 pv = pb4[w * CH + kk];
            acc = dot4i(ev.x, pv.x, acc);
            acc = dot4i(ev.y, pv.y, acc);
            acc = dot4i(ev.z, pv.z, acc);
            acc = dot4i(ev.w, pv.w, acc);
        }
        part[w * ROWS + lane] = acc;
        __syncthreads();

        // ---- epilogue (wave 0): alpha' = Cuse - KLOG + log(acc) + em ----
        if (w == 0) {
            int s4 = part[lane] + part[ROWS + lane]
                   + part[2 * ROWS + lane] + part[3 * ROWS + lane];
            float nv = Cuse - KLOG + __logf((float)s4) + emv;  // log(0) = -inf
            af = (mval > 0.f) ? nv : af;
            publish(W, jblk, (unsigned)t, af, Cnew, lane);
            if (lane == 0) cshare = Cnew;
            Cuse = Cnew;
        }
        // next poll's __syncthreads_and protects all LDS reuse
    }

    // ---- log_Z (block jblk==0): logsum = C - log127 + log(sum p8*eteos) ----
    if (jblk == 0) {
        const u64* R = xb + ((size_t)((Tn - 1) & 1) * Bn + b) * XSTR;
        const unsigned tg = (unsigned)(Tn - 1);
        u64 q = 0;
        bool ok = !act;
        while (true) {
            if (!ok) { q = ald64(R + tid); ok = ((unsigned)(q >> 32) == tg); }
            if (__syncthreads_and(ok)) break;
        }
        float lsum = 0.f;
        if (act && s17 < 16) {
            unsigned pv = (unsigned)q;
            int base = c17 * 64 + s17 * 4;
            lsum = (float)(pv & 0xff)         * eteos[base]
                 + (float)((pv >> 8)  & 0xff) * eteos[base + 1]
                 + (float)((pv >> 16) & 0xff) * eteos[base + 2]
                 + (float)((pv >> 24) & 0xff) * eteos[base + 3];
        }
        lsum = wave_sum_f(lsum);
        if (lane == 0) reds[w] = lsum;
        __syncthreads();
        if (tid == 0) {
            float tot = reds[0] + reds[1] + reds[2] + reds[3];
            float logz = cshare - KL127 + __logf(tot);
            atomicAdd(out, -(scores[b] - logz));
        }
    }
}

extern "C" void kernel_launch(void* const* d_in, const int* in_sizes, int n_in,
                              void* d_out, int out_size, void* d_ws, size_t ws_size,
                              hipStream_t stream) {
    const float* em    = (const float*)d_in[0];
    const int*   tags  = (const int*)d_in[1];
    const float* mask  = (const float*)d_in[2];
    const float* trans = (const float*)d_in[3];
    float* out = (float*)d_out;

    char* ws = (char*)d_ws;
    size_t off = 0;
    unsigned char* eswz = (unsigned char*)(ws + off);
    off += (size_t)ETOT;
    off = (off + 255) & ~(size_t)255;
    float* eteos = (float*)(ws + off); off += JPAD * sizeof(float);
    off = (off + 255) & ~(size_t)255;
    u64* xb = (u64*)(ws + off);        off += (size_t)2 * Bn * XSTR * sizeof(u64);
    off = (off + 255) & ~(size_t)255;
    float* scores = (float*)(ws + off); off += Bn * sizeof(float);

    // ws re-poisoned 0xAA pre-launch: stale tags (0xAAAAAAAA) never match t<128
    (void)hipMemsetAsync(out, 0, sizeof(float), stream);

    build_tabs<<<(ETOT + 255) / 256, 256, 0, stream>>>(trans, eswz, eteos);
    crf_scores<<<Bn, Tn, 0, stream>>>(em, tags, mask, trans, scores);
    crf_fwd<<<dim3(JB, Bn), 256, 0, stream>>>(em, mask, trans, eswz, eteos,
                                              scores, xb, out);
}